// Round 1
// baseline (135.234 us; speedup 1.0000x reference)
//
#include <hip/hip_runtime.h>

// AdditiveAttention: scores[b,h,q,k] = sum_d V[d]*tanh(Wq[q,d]+Wk[k,d]) + bV
// B=2 H=8 Lq=Lk=512 D=64. Compute-bound in exp/rcp (268M tanh terms).
// tanh(x) = 1 - 2/(1+e^{2x}); pre-scale projections by 2*log2(e) so the
// inner loop is add -> v_exp_f32 -> add -> v_rcp_f32 -> fma.

#define BH 16
#define L 512
#define D 64
#define C_SCALE 2.8853900817779268f  // 2*log2(e)

__global__ __launch_bounds__(256) void proj_kernel(
    const float* __restrict__ Q, const float* __restrict__ K,
    const float* __restrict__ W1, const float* __restrict__ b1,
    const float* __restrict__ W2, const float* __restrict__ b2,
    float* __restrict__ wq_all, float* __restrict__ wk_all)
{
    // 4096 blocks: first 2048 project Q rows, last 2048 project K rows.
    // Each block: 4 rows of 64; thread = (local_row, out_col).
    int blk = blockIdx.x;
    bool isK = blk >= 2048;
    const float* __restrict__ X  = isK ? K  : Q;
    const float* __restrict__ W  = isK ? W2 : W1;
    const float* __restrict__ bb = isK ? b2 : b1;
    float* __restrict__ O = isK ? wk_all : wq_all;
    int rb = (isK ? blk - 2048 : blk) * 4;

    __shared__ float xs[4][64];
    int tid = threadIdx.x;
    xs[tid >> 6][tid & 63] = X[rb * 64 + tid];  // coalesced 1KB
    __syncthreads();

    int lr = tid >> 6;   // wave-uniform local row
    int e  = tid & 63;   // output column (coalesced W reads)
    float a0 = 0.f, a1 = 0.f, a2 = 0.f, a3 = 0.f;
    #pragma unroll
    for (int d = 0; d < 64; d += 4) {
        a0 = fmaf(xs[lr][d + 0], W[(d + 0) * 64 + e], a0);
        a1 = fmaf(xs[lr][d + 1], W[(d + 1) * 64 + e], a1);
        a2 = fmaf(xs[lr][d + 2], W[(d + 2) * 64 + e], a2);
        a3 = fmaf(xs[lr][d + 3], W[(d + 3) * 64 + e], a3);
    }
    float r = ((a0 + a1) + (a2 + a3)) + bb[e];
    O[(rb + lr) * 64 + e] = r * C_SCALE;  // pre-scaled for exp2
}

__global__ __launch_bounds__(256) void score_kernel(
    const float* __restrict__ wq_all, const float* __restrict__ wk_all,
    const float* __restrict__ Vv, const float* __restrict__ bV,
    float* __restrict__ out)
{
    // Block = (bh, 32-q tile, 64-k tile). Thread: kg=tid&15 (4 contiguous k),
    // qg=tid>>4 (rows qg and qg+16). 8 accumulators -> 8 independent exp/rcp
    // chains for ILP.
    __shared__ float wq[32][68];    // +4 pad: wave reads rows {0..3} -> banks 0,4,8,12
    __shared__ float wkT[64][68];   // [d][k]: d wave-uniform -> conflict-free b128
    __shared__ float Vs[64];

    int tid = threadIdx.x;
    int blk = blockIdx.x;
    int kt = blk & 7;
    int qt = (blk >> 3) & 15;
    int bh = blk >> 7;

    const float4* __restrict__ wqg = (const float4*)(wq_all + (bh * L + qt * 32) * D);
    const float4* __restrict__ wkg = (const float4*)(wk_all + (bh * L + kt * 64) * D);

    #pragma unroll
    for (int i = 0; i < 2; ++i) {           // 32 rows x 16 float4
        int idx = tid + i * 256;
        int r = idx >> 4, c4 = idx & 15;
        float4 v = wqg[idx];                 // coalesced
        *(float4*)&wq[r][c4 * 4] = v;
    }
    #pragma unroll
    for (int i = 0; i < 4; ++i) {           // 64 rows x 16 float4, transpose into wkT
        int idx = tid + i * 256;
        int r = idx >> 4, c4 = idx & 15;
        float4 v = wkg[idx];                 // coalesced
        int d = c4 * 4;
        wkT[d + 0][r] = v.x; wkT[d + 1][r] = v.y;
        wkT[d + 2][r] = v.z; wkT[d + 3][r] = v.w;
    }
    if (tid < 64) Vs[tid] = Vv[tid];
    __syncthreads();

    int kg = tid & 15;
    int qg = tid >> 4;

    float acc[2][4] = {{0.f, 0.f, 0.f, 0.f}, {0.f, 0.f, 0.f, 0.f}};
    float sv = 0.f;  // sum of V (same for every thread; folded into epilogue)

    for (int d4 = 0; d4 < 64; d4 += 4) {
        float4 q0 = *(const float4*)&wq[qg][d4];
        float4 q1 = *(const float4*)&wq[qg + 16][d4];
        float4 vv = *(const float4*)&Vs[d4];
        sv += (vv.x + vv.y) + (vv.z + vv.w);
        #pragma unroll
        for (int dd = 0; dd < 4; ++dd) {
            float4 kv = *(const float4*)&wkT[d4 + dd][kg * 4];
            float qa = ((const float*)&q0)[dd];
            float qb = ((const float*)&q1)[dd];
            float vd = ((const float*)&vv)[dd];
            float kk[4] = {kv.x, kv.y, kv.z, kv.w};
            #pragma unroll
            for (int j = 0; j < 4; ++j) {
                // pre-scaled: s = c*(wq+wk); e^{2x} = exp2(s)
                float e0 = __builtin_amdgcn_exp2f(qa + kk[j]);
                float r0 = __builtin_amdgcn_rcpf(e0 + 1.f);
                acc[0][j] = fmaf(vd, r0, acc[0][j]);
                float e1 = __builtin_amdgcn_exp2f(qb + kk[j]);
                float r1 = __builtin_amdgcn_rcpf(e1 + 1.f);
                acc[1][j] = fmaf(vd, r1, acc[1][j]);
            }
        }
    }

    // score = bV + sum(V) - 2 * sum_d V[d]/(1+e^{2x_d})
    float base = bV[0] + sv;
    int row0 = (bh * L + qt * 32 + qg) * L + kt * 64 + kg * 4;
    int row1 = row0 + 16 * L;
    float4 o0, o1;
    o0.x = fmaf(-2.f, acc[0][0], base);
    o0.y = fmaf(-2.f, acc[0][1], base);
    o0.z = fmaf(-2.f, acc[0][2], base);
    o0.w = fmaf(-2.f, acc[0][3], base);
    o1.x = fmaf(-2.f, acc[1][0], base);
    o1.y = fmaf(-2.f, acc[1][1], base);
    o1.z = fmaf(-2.f, acc[1][2], base);
    o1.w = fmaf(-2.f, acc[1][3], base);
    *(float4*)&out[row0] = o0;
    *(float4*)&out[row1] = o1;
}

extern "C" void kernel_launch(void* const* d_in, const int* in_sizes, int n_in,
                              void* d_out, int out_size, void* d_ws, size_t ws_size,
                              hipStream_t stream) {
    const float* Q  = (const float*)d_in[0];
    const float* K  = (const float*)d_in[1];
    const float* W1 = (const float*)d_in[2];
    const float* b1 = (const float*)d_in[3];
    const float* W2 = (const float*)d_in[4];
    const float* b2 = (const float*)d_in[5];
    const float* V  = (const float*)d_in[6];
    const float* bV = (const float*)d_in[7];
    float* out = (float*)d_out;

    float* wq_all = (float*)d_ws;                 // BH*L*D floats (2 MB)
    float* wk_all = wq_all + BH * L * D;          // BH*L*D floats (2 MB)

    proj_kernel<<<4096, 256, 0, stream>>>(Q, K, W1, b1, W2, b2, wq_all, wk_all);
    score_kernel<<<2048, 256, 0, stream>>>(wq_all, wk_all, V, bV, out);
}

// Round 3
// 112.615 us; speedup vs baseline: 1.2008x; 1.2008x over previous
//
#include <hip/hip_runtime.h>

// AdditiveAttention: scores[b,h,q,k] = sum_d V[d]*tanh(Wq[q,d]+Wk[k,d]) + bV
// B=2 H=8 Lq=Lk=512 D=64.
//
// tanh(x) = 1 - 2/(1+e^{2x}). Key factorization: e^{2(a+b)} = e^{2a}*e^{2b},
// so exp2 moves to the O(L*D) projection pass (2M exps) and the O(L^2*D)
// inner loop (268M elems) needs NO transcendental except one rcp per TWO
// elements via pairing:
//   V0/d0 + V1/d1 = (V0*d1 + V1*d0) / (d0*d1),  d_i = 1 + Eq_i*Ek_i
// Inner cost: 6 VALU + 0.5 rcp per element = ~10 issue-cyc/elem (was 22).

#define BH 16
#define L 512
#define D 64
#define C_SCALE 2.8853900817779268f  // 2*log2(e)

__global__ __launch_bounds__(256) void proj_kernel(
    const float* __restrict__ Q, const float* __restrict__ K,
    const float* __restrict__ W1, const float* __restrict__ b1,
    const float* __restrict__ W2, const float* __restrict__ b2,
    float* __restrict__ eq_all, float* __restrict__ ek_all)
{
    // 4096 blocks: first 2048 project Q rows, last 2048 project K rows.
    // Output: E = exp2(C * (X@W + b))  (i.e. e^{2*proj}), row-major [row][d].
    int blk = blockIdx.x;
    bool isK = blk >= 2048;
    const float* __restrict__ X  = isK ? K  : Q;
    const float* __restrict__ W  = isK ? W2 : W1;
    const float* __restrict__ bb = isK ? b2 : b1;
    float* __restrict__ O = isK ? ek_all : eq_all;
    int rb = (isK ? blk - 2048 : blk) * 4;

    __shared__ float xs[4][64];
    int tid = threadIdx.x;
    xs[tid >> 6][tid & 63] = X[rb * 64 + tid];  // coalesced 1KB
    __syncthreads();

    int lr = tid >> 6;   // wave-uniform local row
    int e  = tid & 63;   // output column (coalesced W reads)
    float a0 = 0.f, a1 = 0.f, a2 = 0.f, a3 = 0.f;
    #pragma unroll
    for (int d = 0; d < 64; d += 4) {
        a0 = fmaf(xs[lr][d + 0], W[(d + 0) * 64 + e], a0);
        a1 = fmaf(xs[lr][d + 1], W[(d + 1) * 64 + e], a1);
        a2 = fmaf(xs[lr][d + 2], W[(d + 2) * 64 + e], a2);
        a3 = fmaf(xs[lr][d + 3], W[(d + 3) * 64 + e], a3);
    }
    float r = ((a0 + a1) + (a2 + a3)) + bb[e];
    O[(rb + lr) * 64 + e] = __builtin_amdgcn_exp2f(r * C_SCALE);
}

// One rcp + 6 VALU covers a pair of d-elements.
#define PAIR(accref, q0, q1, k0, k1, v0, v1)          \
    {                                                  \
        float d0_  = fmaf((q0), (k0), 1.0f);           \
        float d1_  = fmaf((q1), (k1), 1.0f);           \
        float t_   = (v1) * d0_;                       \
        float num_ = fmaf((v0), d1_, t_);              \
        float pr_  = d0_ * d1_;                        \
        float rc_  = __builtin_amdgcn_rcpf(pr_);       \
        (accref)   = fmaf(num_, rc_, (accref));        \
    }

__global__ __launch_bounds__(256, 8) void score_kernel(
    const float* __restrict__ eq_all, const float* __restrict__ ek_all,
    const float* __restrict__ Vv, const float* __restrict__ bV,
    float* __restrict__ out)
{
    // Block = (bh, 32-q, 32-k). Thread: kg=tid&15 owns k cols {2kg, 2kg+1},
    // qg=tid>>4 owns q rows {qg, qg+16}. 4 accumulators.
    // LDS 17.7KB + VGPR<=64 -> 8 blocks/CU (100% occupancy); 4096 blocks
    // = exactly 16/CU -> clean two-round schedule, no ragged tail.
    __shared__ float eq[32][68];   // row-major [q][d], rows 16B-aligned (272B)
    __shared__ float ek[32][68];   // row-major [k][d], col4 XOR-swizzled by (k>>3)&3
    __shared__ float Vs[64];

    int tid = threadIdx.x;
    int blk = blockIdx.x;
    int kt = blk & 15;
    int qt = (blk >> 4) & 15;
    int bh = blk >> 8;

    const float4* __restrict__ eqg = (const float4*)(eq_all + (bh * L + qt * 32) * D);
    const float4* __restrict__ ekg = (const float4*)(ek_all + (bh * L + kt * 32) * D);

    #pragma unroll
    for (int i = 0; i < 2; ++i) {          // 32 rows x 16 float4 each
        int idx = tid + i * 256;
        int r = idx >> 4, c4 = idx & 15;
        *(float4*)&eq[r][c4 * 4] = eqg[idx];
        int c4s = c4 ^ ((r >> 3) & 3);     // break 4-way read aliasing
        *(float4*)&ek[r][c4s * 4] = ekg[idx];
    }
    if (tid < 64) Vs[tid] = Vv[tid];
    __syncthreads();

    int kg = tid & 15;
    int qg = tid >> 4;
    int swz = (kg >> 2) & 3;               // == ((2kg)>>3)&3 == ((2kg+1)>>3)&3

    const float* __restrict__ eq0p = &eq[qg][0];
    const float* __restrict__ eq1p = &eq[qg + 16][0];
    const float* __restrict__ ek0p = &ek[kg * 2][0];
    const float* __restrict__ ek1p = &ek[kg * 2 + 1][0];

    float acc00 = 0.f, acc01 = 0.f, acc10 = 0.f, acc11 = 0.f;

    #pragma unroll 4
    for (int d4 = 0; d4 < 16; ++d4) {
        float4 vq0 = *(const float4*)(eq0p + d4 * 4);       // broadcast
        float4 vq1 = *(const float4*)(eq1p + d4 * 4);       // broadcast
        int dc = (d4 ^ swz) * 4;
        float4 vk0 = *(const float4*)(ek0p + dc);           // 2-way phase, free
        float4 vk1 = *(const float4*)(ek1p + dc);
        float4 vv  = *(const float4*)&Vs[d4 * 4];           // broadcast

        PAIR(acc00, vq0.x, vq0.y, vk0.x, vk0.y, vv.x, vv.y);
        PAIR(acc00, vq0.z, vq0.w, vk0.z, vk0.w, vv.z, vv.w);
        PAIR(acc01, vq0.x, vq0.y, vk1.x, vk1.y, vv.x, vv.y);
        PAIR(acc01, vq0.z, vq0.w, vk1.z, vk1.w, vv.z, vv.w);
        PAIR(acc10, vq1.x, vq1.y, vk0.x, vk0.y, vv.x, vv.y);
        PAIR(acc10, vq1.z, vq1.w, vk0.z, vk0.w, vv.z, vv.w);
        PAIR(acc11, vq1.x, vq1.y, vk1.x, vk1.y, vv.x, vv.y);
        PAIR(acc11, vq1.z, vq1.w, vk1.z, vk1.w, vv.z, vv.w);
    }

    // sum(V): uniform, computed once in epilogue (hoisted out of hot loop)
    float sv = 0.f;
    #pragma unroll
    for (int d4 = 0; d4 < 16; ++d4) {
        float4 vv = *(const float4*)&Vs[d4 * 4];
        sv += (vv.x + vv.y) + (vv.z + vv.w);
    }

    // score = bV + sum(V) - 2 * sum_d V[d]/(1+e^{2x_d})
    float base = bV[0] + sv;
    int row0 = (bh * L + qt * 32 + qg) * L + kt * 32 + kg * 2;
    int row1 = row0 + 16 * L;
    float2 o0, o1;
    o0.x = fmaf(-2.f, acc00, base);
    o0.y = fmaf(-2.f, acc01, base);
    o1.x = fmaf(-2.f, acc10, base);
    o1.y = fmaf(-2.f, acc11, base);
    *(float2*)&out[row0] = o0;
    *(float2*)&out[row1] = o1;
}

extern "C" void kernel_launch(void* const* d_in, const int* in_sizes, int n_in,
                              void* d_out, int out_size, void* d_ws, size_t ws_size,
                              hipStream_t stream) {
    const float* Q  = (const float*)d_in[0];
    const float* K  = (const float*)d_in[1];
    const float* W1 = (const float*)d_in[2];
    const float* b1 = (const float*)d_in[3];
    const float* W2 = (const float*)d_in[4];
    const float* b2 = (const float*)d_in[5];
    const float* V  = (const float*)d_in[6];
    const float* bV = (const float*)d_in[7];
    float* out = (float*)d_out;

    float* eq_all = (float*)d_ws;                 // BH*L*D floats (2 MB)
    float* ek_all = eq_all + BH * L * D;          // BH*L*D floats (2 MB)

    proj_kernel<<<4096, 256, 0, stream>>>(Q, K, W1, b1, W2, b2, eq_all, ek_all);
    score_kernel<<<4096, 256, 0, stream>>>(eq_all, ek_all, V, bV, out);
}